// Round 14
// baseline (11970.471 us; speedup 1.0000x reference)
//
#include <hip/hip_runtime.h>

typedef unsigned int uint32;
typedef unsigned long long uint64;
typedef _Float16 f16;
typedef _Float16 half8 __attribute__((ext_vector_type(8)));
typedef float floatx4 __attribute__((ext_vector_type(4)));

#define HD    512    // hidden
#define NBAT  256    // batch
#define CTXL  512    // context length
#define NPRED 64     // prediction length
#define NBLK  256
#define NTHR  256
#define NSTR  4      // independent batch stripes (64 rows each)
#define SBLK  64     // blocks per stripe (32 A + 32 B)
#define LDS_BYTES (6*16*64*16)   // 98304 B: fragment-linear weights (B uses all, A half)
#define NGEN  640u               // stripe barriers per launch (1 init + 639 intervals)

// Scratch in device globals. ALL cross-block data via relaxed agent-scope
// atomics (device-coherent path, NO cache flushes in the data path).
// BARRIER ORDERING (R9/R13 lessons): vmcnt-ack of sc1 stores is NOT commit at
// the coherence point. Arrival must be a RELEASE RMW (emits wbl2+drain before
// the add) and consumers must ACQUIRE-fence after poll-success. Relaxed-RMW
// arrival is only probabilistically safe (failed 1-in-~100 launches in R13).
__device__ __attribute__((aligned(256))) f16   g_h0[2][NBAT][HD];
__device__ __attribute__((aligned(256))) f16   g_h1[2][NBAT][HD];
__device__ __attribute__((aligned(256))) float g_yacc[NPRED][NBAT];
__device__ __attribute__((aligned(256))) float g_scale[NBAT];
// Per stripe: 16 arrival lines (64B apart), 4 blocks add to each per barrier.
__device__ __attribute__((aligned(256))) uint32 g_sline[NSTR*16*16];
__device__ __attribute__((aligned(256))) uint32 g_sepoch[NSTR*64];  // per-stripe launch count

__device__ __forceinline__ float sigm(float x){ return 1.f/(1.f+__expf(-x)); }
__device__ __forceinline__ float tanh_(float x){ return 1.f - 2.f/(__expf(2.f*x)+1.f); }

// ---- device-coherent (no-flush) access helpers -----------------------------
__device__ __forceinline__ uint32 ld_u32_dc(const uint32* p){
  return __hip_atomic_load(p, __ATOMIC_RELAXED, __HIP_MEMORY_SCOPE_AGENT);
}
__device__ __forceinline__ void st_u32_dc(uint32* p, uint32 v){
  __hip_atomic_store(p, v, __ATOMIC_RELAXED, __HIP_MEMORY_SCOPE_AGENT);
}
__device__ __forceinline__ void st_u64_dc(uint64* p, uint64 v){
  __hip_atomic_store(p, v, __ATOMIC_RELAXED, __HIP_MEMORY_SCOPE_AGENT);
}
__device__ __forceinline__ float ld_f32_dc(const float* p){
  return __hip_atomic_load(p, __ATOMIC_RELAXED, __HIP_MEMORY_SCOPE_AGENT);
}
__device__ __forceinline__ void st_f32_dc(float* p, float v){
  __hip_atomic_store(p, v, __ATOMIC_RELAXED, __HIP_MEMORY_SCOPE_AGENT);
}
__device__ __forceinline__ float ld_f16_dc(const f16* p){
  unsigned short u = __hip_atomic_load((const unsigned short*)p, __ATOMIC_RELAXED, __HIP_MEMORY_SCOPE_AGENT);
  union { unsigned short u; f16 h; } c; c.u = u; return (float)c.h;
}
__device__ __forceinline__ void st_f16_dc(f16* p, float x){
  union { unsigned short u; f16 h; } c; c.h = (f16)x;
  __hip_atomic_store((unsigned short*)p, c.u, __ATOMIC_RELAXED, __HIP_MEMORY_SCOPE_AGENT);
}
__device__ __forceinline__ half8 ld_half8_dc(const f16* p){   // 2x b64 coherent loads
  const uint64* q = (const uint64*)p;
  union { uint64 u[2]; half8 h; } r;
  r.u[0] = __hip_atomic_load(q+0, __ATOMIC_RELAXED, __HIP_MEMORY_SCOPE_AGENT);
  r.u[1] = __hip_atomic_load(q+1, __ATOMIC_RELAXED, __HIP_MEMORY_SCOPE_AGENT);
  return r.h;
}

// Stripe barrier, architecturally ordered:
//   producer: workgroup release fence + syncthreads (collect all waves'
//             stores) -> RELEASE fetch_add at agent scope (wbl2+drain BEFORE
//             the add commits -> data provably visible before arrival).
//   consumer: relaxed ballot-gather poll; on success an agent ACQUIRE fence,
//             then syncthreads (chains visibility to all waves).
// Arrivals spread over 16 lines (4 blocks/line) to avoid same-line RMW
// serialization (R8 lesson). tgt4 = 4*(base+gen); wrap-safe compare.
__device__ __forceinline__ void sbar(uint32* lines, int rr, uint32 tgt4){
  __builtin_amdgcn_fence(__ATOMIC_RELEASE, "workgroup");
  __syncthreads();
  if (threadIdx.x == 0)
    __hip_atomic_fetch_add(&lines[(rr & 15)*16], 1u, __ATOMIC_RELEASE, __HIP_MEMORY_SCOPE_AGENT);
  if (threadIdx.x < 64) {
    const int lane = threadIdx.x;
    const uint32* fp = &lines[(lane & 15)*16];
    for (;;) {
      bool ok = (lane >= 16) || ((int)(ld_u32_dc(fp) - tgt4) >= 0);
      if (__ballot(ok) == ~0ull) break;
      __builtin_amdgcn_s_sleep(1);
    }
  }
  __builtin_amdgcn_fence(__ATOMIC_ACQUIRE, "agent");
  __syncthreads();
}

// Persistent 2-layer GRU + AR decode; 4 independent 64-row stripes.
// Stripe s: blocks 64s..64s+63. rr<32: A (layer 0); rr>=32: B (layer 1).
// Weights in fragment-linear LDS (conflict-free, R12). A-operands batch-loaded
// into registers (one coherent-load drain per matrix, R13).
// Interval i: A does layer-0 step i (enc); B does layer-1 step i-1.
// Decode step d: A at interval 513+2d, B at 514+2d.
__global__ __launch_bounds__(NTHR, 1) void rnn_persist(
    const float* __restrict__ ctx,    // [256][512] f32
    const float* __restrict__ Wih0,   // [1536]
    const float* __restrict__ Whh0,   // [1536][512]
    const float* __restrict__ bih0,   // [1536]
    const float* __restrict__ bhh0,   // [1536]
    const float* __restrict__ Wih1,   // [1536][512]
    const float* __restrict__ Whh1,   // [1536][512]
    const float* __restrict__ bih1,   // [1536]
    const float* __restrict__ bhh1,   // [1536]
    const float* __restrict__ Wout,   // [512]
    const float* __restrict__ boutp,  // [1]
    float* __restrict__ out)          // [256][64] f32
{
  extern __shared__ char smem_raw[];
  f16* wlds = (f16*)smem_raw;
  __shared__ float wsum[4];

  const int tid  = threadIdx.x;
  const int bid  = blockIdx.x;
  const int sid  = bid >> 6;         // stripe
  const int rr_  = bid & 63;
  const bool isA = rr_ < 32;
  const int ng   = isA ? rr_ : rr_ - 32;
  const int Mbase = sid * 64;        // batch-row base of stripe
  const int s0    = ng * 16;         // hidden-col base of this block
  const int w    = tid >> 6;
  const int lane = tid & 63;
  const int quad = lane >> 4;
  const int l16  = lane & 15;

  uint32* lines = &g_sline[sid*256];
  const uint32 E = ld_u32_dc(&g_sepoch[sid*64]);
  const uint32 base = E * NGEN;

  // ---------------- init (all stripe-local): scale, zero h, zero y ----------
  {
    const int b = bid;               // block bid handles batch row bid
    float s2 = 0.f;
    for (int k = tid; k < CTXL; k += NTHR) s2 += ctx[b*CTXL + k];
    #pragma unroll
    for (int m = 1; m < 64; m <<= 1) s2 += __shfl_xor(s2, m, 64);
    if (lane == 0) wsum[w] = s2;
    __syncthreads();
    float tot = wsum[0] + wsum[1] + wsum[2] + wsum[3];
    float sc  = fmaxf(fabsf(tot / (float)CTXL), 1e-5f);
    if (tid == 0) st_f32_dc(&g_scale[b], sc);
    uint64* h00 = (uint64*)&g_h0[0][b][0]; uint64* h01 = (uint64*)&g_h0[1][b][0];
    uint64* h10 = (uint64*)&g_h1[0][b][0]; uint64* h11 = (uint64*)&g_h1[1][b][0];
    for (int k = tid; k < HD/4; k += NTHR) {
      st_u64_dc(h00+k, 0ull); st_u64_dc(h01+k, 0ull);
      st_u64_dc(h10+k, 0ull); st_u64_dc(h11+k, 0ull);
    }
    if (tid < 64) st_f32_dc(&g_yacc[rr_][Mbase + tid], 0.f);
  }

  // -------- weights -> fragment-linear LDS (f32 -> f16, conflict-free) ------
  // frag index mg: A: 0..2 = Whh0 gate g. B: 0..2 = Wih1 gates, 3..5 = Whh1.
  // halves offset of (mg,kc,lane) = ((mg*16+kc)*64 + lane)*8
  {
    const int nfrag = isA ? (3*16*64) : (6*16*64);
    for (int idx = tid; idx < nfrag; idx += NTHR) {
      const int ln = idx & 63;
      const int kc = (idx >> 6) & 15;
      const int mg = idx >> 10;
      const float* Wsrc;
      int g;
      if (isA)            { Wsrc = Whh0; g = mg; }
      else if (mg < 3)    { Wsrc = Wih1; g = mg; }
      else                { Wsrc = Whh1; g = mg - 3; }
      const float* src = Wsrc + (size_t)(g*HD + s0 + (ln & 15))*HD + (ln >> 4)*8 + kc*32;
      f16* dst = wlds + (size_t)idx*8;
      #pragma unroll
      for (int j = 0; j < 8; ++j) dst[j] = (f16)src[j];
    }
  }

  // ---------------- per-thread constants ------------------------------------
  float wi_r=0, wi_z=0, wi_n=0, bi_r, bi_z, bi_n, bh_r, bh_z, bh_n;
  float woutj=0, boutv=0;
  const int jcol = s0 + l16;
  const int mf = w;                  // 4 waves x 16 batch rows = 64 rows
  if (isA) {
    wi_r = Wih0[jcol]; wi_z = Wih0[HD + jcol]; wi_n = Wih0[2*HD + jcol];
    bi_r = bih0[jcol]; bi_z = bih0[HD + jcol]; bi_n = bih0[2*HD + jcol];
    bh_r = bhh0[jcol]; bh_z = bhh0[HD + jcol]; bh_n = bhh0[2*HD + jcol];
  } else {
    bi_r = bih1[jcol]; bi_z = bih1[HD + jcol]; bi_n = bih1[2*HD + jcol];
    bh_r = bhh1[jcol]; bh_z = bhh1[HD + jcol]; bh_n = bhh1[2*HD + jcol];
    woutj = Wout[jcol]; boutv = boutp[0];
  }

  uint32 gen = 1;
  sbar(lines, rr_, (base + gen)*4u); gen++;   // stripe init complete

  // preload scale for my 4 output rows (stable after barrier 1)
  float scl[4];
  {
    const int bb = Mbase + mf*16 + quad*4;
    #pragma unroll
    for (int reg = 0; reg < 4; ++reg) scl[reg] = ld_f32_dc(&g_scale[bb + reg]);
  }

  // ---------------- interval loop -------------------------------------------
  for (int i = 0; i <= 638; ++i) {
    if (isA) {
      int sA = -1;
      if (i <= 511) sA = i;
      else if (i >= 513 && ((i-513)&1) == 0 && (i-513)/2 <= 62)
        sA = 512 + (i-513)/2;
      if (sA >= 0) {
        const f16* hrd = &g_h0[sA & 1][0][0];
        f16*       hwr = &g_h0[(sA+1) & 1][0][0];
        const int b0 = Mbase + mf*16 + quad*4;
        // prefetch epilogue operands (drain overlaps the big batch below)
        float hold[4], xv[4];
        #pragma unroll
        for (int reg = 0; reg < 4; ++reg) {
          hold[reg] = ld_f16_dc(&hrd[(size_t)(b0+reg)*HD + jcol]);
          xv[reg] = (sA < 512) ? (ctx[(b0+reg)*CTXL + sA] / scl[reg])
                               : ld_f32_dc(&g_yacc[sA-512][b0+reg]);
        }
        // batch ALL A-operand loads (32 b64 in flight, ONE drain point)
        const int arow = Mbase + mf*16 + l16;
        const f16* aptr = hrd + (size_t)arow*HD + quad*8;
        half8 av[16];
        #pragma unroll
        for (int kc = 0; kc < 16; ++kc) av[kc] = ld_half8_dc(aptr + kc*32);
        floatx4 ar = {0.f,0.f,0.f,0.f}, az = ar, an_ = ar;
        const f16* fb = wlds + (size_t)lane*8;       // fragment-linear base
        #pragma unroll
        for (int kc = 0; kc < 16; ++kc) {
          const f16* fkc = fb + (size_t)kc*512;
          half8 v;
          v = *(const half8*)(fkc);          ar  = __builtin_amdgcn_mfma_f32_16x16x32_f16(av[kc], v, ar,  0,0,0);
          v = *(const half8*)(fkc + 8192);   az  = __builtin_amdgcn_mfma_f32_16x16x32_f16(av[kc], v, az,  0,0,0);
          v = *(const half8*)(fkc + 16384);  an_ = __builtin_amdgcn_mfma_f32_16x16x32_f16(av[kc], v, an_, 0,0,0);
        }
        #pragma unroll
        for (int reg = 0; reg < 4; ++reg) {
          float hgr = ar[reg] + bh_r, hgz = az[reg] + bh_z, hgn = an_[reg] + bh_n;
          float rg  = sigm(fmaf(xv[reg], wi_r, bi_r) + hgr);
          float zg  = sigm(fmaf(xv[reg], wi_z, bi_z) + hgz);
          float ng_ = tanh_(fmaf(xv[reg], wi_n, bi_n) + rg*hgn);
          st_f16_dc(&hwr[(size_t)(b0+reg)*HD + jcol], (1.f - zg)*ng_ + zg*hold[reg]);
        }
      }
    } else {
      int sB = -1;
      if (i >= 1 && i <= 512) sB = i - 1;
      else if (i >= 514 && ((i-514)&1) == 0 && (i-514)/2 <= 62)
        sB = 512 + (i-514)/2;
      if (sB >= 0) {
        const f16* h0rd = &g_h0[(sB+1) & 1][0][0];   // layer-0 output of step sB
        const f16* h1rd = &g_h1[sB & 1][0][0];
        f16*       h1wr = &g_h1[(sB+1) & 1][0][0];
        const int b0 = Mbase + mf*16 + quad*4;
        float hold[4];
        #pragma unroll
        for (int reg = 0; reg < 4; ++reg)
          hold[reg] = ld_f16_dc(&h1rd[(size_t)(b0+reg)*HD + jcol]);
        // batch BOTH A-operand matrices into registers (issue all, then use;
        // a1's drain overlaps a0's MFMA chain)
        const int arow = Mbase + mf*16 + l16;
        const f16* a0p = h0rd + (size_t)arow*HD + quad*8;
        const f16* a1p = h1rd + (size_t)arow*HD + quad*8;
        half8 a0v[16], a1v[16];
        #pragma unroll
        for (int kc = 0; kc < 16; ++kc) a0v[kc] = ld_half8_dc(a0p + kc*32);
        #pragma unroll
        for (int kc = 0; kc < 16; ++kc) a1v[kc] = ld_half8_dc(a1p + kc*32);
        floatx4 xr = {0.f,0.f,0.f,0.f}, xz = xr, xn = xr, hr = xr, hz = xr, hn = xr;
        const f16* fb = wlds + (size_t)lane*8;       // fragment-linear base
        #pragma unroll
        for (int kc = 0; kc < 16; ++kc) {
          const f16* fkc = fb + (size_t)kc*512;
          half8 v;
          v = *(const half8*)(fkc);           xr = __builtin_amdgcn_mfma_f32_16x16x32_f16(a0v[kc], v, xr, 0,0,0);
          v = *(const half8*)(fkc + 8192);    xz = __builtin_amdgcn_mfma_f32_16x16x32_f16(a0v[kc], v, xz, 0,0,0);
          v = *(const half8*)(fkc + 16384);   xn = __builtin_amdgcn_mfma_f32_16x16x32_f16(a0v[kc], v, xn, 0,0,0);
        }
        #pragma unroll
        for (int kc = 0; kc < 16; ++kc) {
          const f16* fkc = fb + (size_t)kc*512;
          half8 v;
          v = *(const half8*)(fkc + 24576);   hr = __builtin_amdgcn_mfma_f32_16x16x32_f16(a1v[kc], v, hr, 0,0,0);
          v = *(const half8*)(fkc + 32768);   hz = __builtin_amdgcn_mfma_f32_16x16x32_f16(a1v[kc], v, hz, 0,0,0);
          v = *(const half8*)(fkc + 40960);   hn = __builtin_amdgcn_mfma_f32_16x16x32_f16(a1v[kc], v, hn, 0,0,0);
        }
        #pragma unroll
        for (int reg = 0; reg < 4; ++reg) {
          const int b = b0 + reg;
          float rg  = sigm(xr[reg] + bi_r + hr[reg] + bh_r);
          float zg  = sigm(xz[reg] + bi_z + hz[reg] + bh_z);
          float ng_ = tanh_(xn[reg] + bi_n + rg*(hn[reg] + bh_n));
          float hnew = (1.f - zg)*ng_ + zg*hold[reg];
          st_f16_dc(&h1wr[(size_t)b*HD + jcol], hnew);
          if (sB >= 511) {                       // emit forecast partials
            float c = hnew * woutj;
            c += __shfl_xor(c, 1, 64); c += __shfl_xor(c, 2, 64);
            c += __shfl_xor(c, 4, 64); c += __shfl_xor(c, 8, 64);
            if (l16 == 0) {
              if (ng == 0) c += boutv;           // bias exactly once per row
              atomicAdd(&g_yacc[sB-511][b], c);  // device-scope, coherent path
            }
          }
        }
      }
    }
    sbar(lines, rr_, (base + gen)*4u); gen++;
  }

  // ---------------- stripe epoch advance + stripe-local output --------------
  if (rr_ == 0 && tid == 0)
    st_u32_dc(&g_sepoch[sid*64], E + 1u);

  if (tid < 64) {
    const int b = Mbase + tid;
    out[b*NPRED + rr_] = ld_f32_dc(&g_yacc[rr_][b]) * ld_f32_dc(&g_scale[b]);
  }
}

extern "C" void kernel_launch(void* const* d_in, const int* in_sizes, int n_in,
                              void* d_out, int out_size, void* d_ws, size_t ws_size,
                              hipStream_t stream) {
  const float* ctx   = (const float*)d_in[0];
  const float* Wih0  = (const float*)d_in[1];
  const float* Whh0  = (const float*)d_in[2];
  const float* bih0  = (const float*)d_in[3];
  const float* bhh0  = (const float*)d_in[4];
  const float* Wih1  = (const float*)d_in[5];
  const float* Whh1  = (const float*)d_in[6];
  const float* bih1  = (const float*)d_in[7];
  const float* bhh1  = (const float*)d_in[8];
  const float* Wout  = (const float*)d_in[9];
  const float* boutp = (const float*)d_in[10];
  float* out = (float*)d_out;

  hipFuncSetAttribute(reinterpret_cast<const void*>(rnn_persist),
                      hipFuncAttributeMaxDynamicSharedMemorySize, LDS_BYTES);

  void* params[] = {
    (void*)&ctx, (void*)&Wih0, (void*)&Whh0, (void*)&bih0, (void*)&bhh0,
    (void*)&Wih1, (void*)&Whh1, (void*)&bih1, (void*)&bhh1,
    (void*)&Wout, (void*)&boutp, (void*)&out
  };
  hipLaunchCooperativeKernel(reinterpret_cast<void*>(rnn_persist),
                             dim3(NBLK), dim3(NTHR), params, LDS_BYTES, stream);
}

// Round 15
// 7205.496 us; speedup vs baseline: 1.6613x; 1.6613x over previous
//
#include <hip/hip_runtime.h>

typedef unsigned int uint32;
typedef unsigned long long uint64;
typedef _Float16 f16;
typedef _Float16 half8 __attribute__((ext_vector_type(8)));
typedef float floatx4 __attribute__((ext_vector_type(4)));

#define HD    512    // hidden
#define NBAT  256    // batch
#define CTXL  512    // context length
#define NPRED 64     // prediction length
#define NBLK  256
#define NTHR  256
#define NSTR  4      // independent batch stripes (64 rows each)
#define SBLK  64     // blocks per stripe (32 A + 32 B)
#define LDS_BYTES (6*16*64*16)   // 98304 B: fragment-linear weights (B uses all, A half)
#define NGEN  640u               // stripe barriers per launch (1 init + 639 intervals)

// Scratch in device globals. ALL cross-block data via relaxed agent-scope
// atomics (MALL-direct, never in L1/L2 -> consumers can't read stale cache).
// PRODUCER ORDERING (R9/R13/R14 lessons): vmcnt-ack of an sc1 store is NOT
// commit at the MALL; a later arrival RMW can overtake it. R14's release-RMW +
// agent-acquire fixed it but cost ~9 us/interval (buffer_inv x4 waves).
// This round: SAME-ADDRESS LOAD-BACK. Per-location coherence => a returned
// load-back proves the store committed; draining load-backs (vmcnt) before the
// relaxed arrival gives architectural ordering with zero cache-walk ops.
__device__ __attribute__((aligned(256))) f16   g_h0[2][NBAT][HD];
__device__ __attribute__((aligned(256))) f16   g_h1[2][NBAT][HD];
__device__ __attribute__((aligned(256))) float g_yacc[NPRED][NBAT];
__device__ __attribute__((aligned(256))) float g_scale[NBAT];
// Per stripe: 16 arrival lines (64B apart), 4 blocks add to each per barrier.
__device__ __attribute__((aligned(256))) uint32 g_sline[NSTR*16*16];
__device__ __attribute__((aligned(256))) uint32 g_sepoch[NSTR*64];  // per-stripe launch count

__device__ __forceinline__ float sigm(float x){ return 1.f/(1.f+__expf(-x)); }
__device__ __forceinline__ float tanh_(float x){ return 1.f - 2.f/(__expf(2.f*x)+1.f); }

// ---- device-coherent (no-flush) access helpers -----------------------------
__device__ __forceinline__ uint32 ld_u32_dc(const uint32* p){
  return __hip_atomic_load(p, __ATOMIC_RELAXED, __HIP_MEMORY_SCOPE_AGENT);
}
__device__ __forceinline__ void st_u32_dc(uint32* p, uint32 v){
  __hip_atomic_store(p, v, __ATOMIC_RELAXED, __HIP_MEMORY_SCOPE_AGENT);
}
__device__ __forceinline__ void st_u64_dc(uint64* p, uint64 v){
  __hip_atomic_store(p, v, __ATOMIC_RELAXED, __HIP_MEMORY_SCOPE_AGENT);
}
__device__ __forceinline__ float ld_f32_dc(const float* p){
  return __hip_atomic_load(p, __ATOMIC_RELAXED, __HIP_MEMORY_SCOPE_AGENT);
}
__device__ __forceinline__ void st_f32_dc(float* p, float v){
  __hip_atomic_store(p, v, __ATOMIC_RELAXED, __HIP_MEMORY_SCOPE_AGENT);
}
__device__ __forceinline__ float ld_f16_dc(const f16* p){
  unsigned short u = __hip_atomic_load((const unsigned short*)p, __ATOMIC_RELAXED, __HIP_MEMORY_SCOPE_AGENT);
  union { unsigned short u; f16 h; } c; c.u = u; return (float)c.h;
}
__device__ __forceinline__ void st_f16_dc(f16* p, float x){
  union { unsigned short u; f16 h; } c; c.h = (f16)x;
  __hip_atomic_store((unsigned short*)p, c.u, __ATOMIC_RELAXED, __HIP_MEMORY_SCOPE_AGENT);
}
__device__ __forceinline__ half8 ld_half8_dc(const f16* p){   // 2x b64 coherent loads
  const uint64* q = (const uint64*)p;
  union { uint64 u[2]; half8 h; } r;
  r.u[0] = __hip_atomic_load(q+0, __ATOMIC_RELAXED, __HIP_MEMORY_SCOPE_AGENT);
  r.u[1] = __hip_atomic_load(q+1, __ATOMIC_RELAXED, __HIP_MEMORY_SCOPE_AGENT);
  return r.h;
}

// FAST stripe barrier (steady state): workgroup release fence (s_waitcnt only
// -> drains data stores AND the epilogue load-backs), syncthreads, RELAXED
// arrival RMW (load-backs already prove data commit), ballot-gather poll.
// Arrivals spread over 16 lines (4 blocks/line). tgt4 = 4*(base+gen).
__device__ __forceinline__ void sbar_fast(uint32* lines, int rr, uint32 tgt4){
  __builtin_amdgcn_fence(__ATOMIC_RELEASE, "workgroup");
  __syncthreads();
  if (threadIdx.x == 0)
    __hip_atomic_fetch_add(&lines[(rr & 15)*16], 1u, __ATOMIC_RELAXED, __HIP_MEMORY_SCOPE_AGENT);
  if (threadIdx.x < 64) {
    const int lane = threadIdx.x;
    const uint32* fp = &lines[(lane & 15)*16];
    for (;;) {
      bool ok = (lane >= 16) || ((int)(ld_u32_dc(fp) - tgt4) >= 0);
      if (__ballot(ok) == ~0ull) break;
      __builtin_amdgcn_s_sleep(1);
    }
  }
  __syncthreads();
}

// STRONG barrier (init only, once per launch): full release RMW + agent
// acquire — covers the init phase's plain stores without load-backs.
__device__ __forceinline__ void sbar_strong(uint32* lines, int rr, uint32 tgt4){
  __builtin_amdgcn_fence(__ATOMIC_RELEASE, "workgroup");
  __syncthreads();
  if (threadIdx.x == 0)
    __hip_atomic_fetch_add(&lines[(rr & 15)*16], 1u, __ATOMIC_RELEASE, __HIP_MEMORY_SCOPE_AGENT);
  if (threadIdx.x < 64) {
    const int lane = threadIdx.x;
    const uint32* fp = &lines[(lane & 15)*16];
    for (;;) {
      bool ok = (lane >= 16) || ((int)(ld_u32_dc(fp) - tgt4) >= 0);
      if (__ballot(ok) == ~0ull) break;
      __builtin_amdgcn_s_sleep(1);
    }
  }
  __builtin_amdgcn_fence(__ATOMIC_ACQUIRE, "agent");
  __syncthreads();
}

// Persistent 2-layer GRU + AR decode; 4 independent 64-row stripes.
// Stripe s: blocks 64s..64s+63. rr<32: A (layer 0); rr>=32: B (layer 1).
// Weights in fragment-linear LDS (conflict-free, R12). A-operands batch-loaded
// into registers (one coherent-load drain per matrix, R13). Producer commit
// proven via same-address load-backs folded into a never-true guard (R15).
// Interval i: A does layer-0 step i (enc); B does layer-1 step i-1.
// Decode step d: A at interval 513+2d, B at 514+2d.
__global__ __launch_bounds__(NTHR, 1) void rnn_persist(
    const float* __restrict__ ctx,    // [256][512] f32
    const float* __restrict__ Wih0,   // [1536]
    const float* __restrict__ Whh0,   // [1536][512]
    const float* __restrict__ bih0,   // [1536]
    const float* __restrict__ bhh0,   // [1536]
    const float* __restrict__ Wih1,   // [1536][512]
    const float* __restrict__ Whh1,   // [1536][512]
    const float* __restrict__ bih1,   // [1536]
    const float* __restrict__ bhh1,   // [1536]
    const float* __restrict__ Wout,   // [512]
    const float* __restrict__ boutp,  // [1]
    float* __restrict__ out)          // [256][64] f32
{
  extern __shared__ char smem_raw[];
  f16* wlds = (f16*)smem_raw;
  __shared__ float wsum[4];

  const int tid  = threadIdx.x;
  const int bid  = blockIdx.x;
  const int sid  = bid >> 6;         // stripe
  const int rr_  = bid & 63;
  const bool isA = rr_ < 32;
  const int ng   = isA ? rr_ : rr_ - 32;
  const int Mbase = sid * 64;        // batch-row base of stripe
  const int s0    = ng * 16;         // hidden-col base of this block
  const int w    = tid >> 6;
  const int lane = tid & 63;
  const int quad = lane >> 4;
  const int l16  = lane & 15;

  uint32* lines = &g_sline[sid*256];
  const uint32 E = ld_u32_dc(&g_sepoch[sid*64]);
  const uint32 base = E * NGEN;

  // ---------------- init (all stripe-local): scale, zero h, zero y ----------
  {
    const int b = bid;               // block bid handles batch row bid
    float s2 = 0.f;
    for (int k = tid; k < CTXL; k += NTHR) s2 += ctx[b*CTXL + k];
    #pragma unroll
    for (int m = 1; m < 64; m <<= 1) s2 += __shfl_xor(s2, m, 64);
    if (lane == 0) wsum[w] = s2;
    __syncthreads();
    float tot = wsum[0] + wsum[1] + wsum[2] + wsum[3];
    float sc  = fmaxf(fabsf(tot / (float)CTXL), 1e-5f);
    if (tid == 0) st_f32_dc(&g_scale[b], sc);
    uint64* h00 = (uint64*)&g_h0[0][b][0]; uint64* h01 = (uint64*)&g_h0[1][b][0];
    uint64* h10 = (uint64*)&g_h1[0][b][0]; uint64* h11 = (uint64*)&g_h1[1][b][0];
    for (int k = tid; k < HD/4; k += NTHR) {
      st_u64_dc(h00+k, 0ull); st_u64_dc(h01+k, 0ull);
      st_u64_dc(h10+k, 0ull); st_u64_dc(h11+k, 0ull);
    }
    if (tid < 64) st_f32_dc(&g_yacc[rr_][Mbase + tid], 0.f);
  }

  // -------- weights -> fragment-linear LDS (f32 -> f16, conflict-free) ------
  // frag index mg: A: 0..2 = Whh0 gate g. B: 0..2 = Wih1 gates, 3..5 = Whh1.
  // halves offset of (mg,kc,lane) = ((mg*16+kc)*64 + lane)*8
  {
    const int nfrag = isA ? (3*16*64) : (6*16*64);
    for (int idx = tid; idx < nfrag; idx += NTHR) {
      const int ln = idx & 63;
      const int kc = (idx >> 6) & 15;
      const int mg = idx >> 10;
      const float* Wsrc;
      int g;
      if (isA)            { Wsrc = Whh0; g = mg; }
      else if (mg < 3)    { Wsrc = Wih1; g = mg; }
      else                { Wsrc = Whh1; g = mg - 3; }
      const float* src = Wsrc + (size_t)(g*HD + s0 + (ln & 15))*HD + (ln >> 4)*8 + kc*32;
      f16* dst = wlds + (size_t)idx*8;
      #pragma unroll
      for (int j = 0; j < 8; ++j) dst[j] = (f16)src[j];
    }
  }

  // ---------------- per-thread constants ------------------------------------
  float wi_r=0, wi_z=0, wi_n=0, bi_r, bi_z, bi_n, bh_r, bh_z, bh_n;
  float woutj=0, boutv=0;
  const int jcol = s0 + l16;
  const int mf = w;                  // 4 waves x 16 batch rows = 64 rows
  if (isA) {
    wi_r = Wih0[jcol]; wi_z = Wih0[HD + jcol]; wi_n = Wih0[2*HD + jcol];
    bi_r = bih0[jcol]; bi_z = bih0[HD + jcol]; bi_n = bih0[2*HD + jcol];
    bh_r = bhh0[jcol]; bh_z = bhh0[HD + jcol]; bh_n = bhh0[2*HD + jcol];
  } else {
    bi_r = bih1[jcol]; bi_z = bih1[HD + jcol]; bi_n = bih1[2*HD + jcol];
    bh_r = bhh1[jcol]; bh_z = bhh1[HD + jcol]; bh_n = bhh1[2*HD + jcol];
    woutj = Wout[jcol]; boutv = boutp[0];
  }

  uint32 gen = 1;
  sbar_strong(lines, rr_, (base + gen)*4u); gen++;   // stripe init complete

  // preload scale for my 4 output rows (stable after barrier 1)
  float scl[4];
  {
    const int bb = Mbase + mf*16 + quad*4;
    #pragma unroll
    for (int reg = 0; reg < 4; ++reg) scl[reg] = ld_f32_dc(&g_scale[bb + reg]);
  }

  float chk = 0.f;   // accumulates load-back values; guard below is never true

  // ---------------- interval loop -------------------------------------------
  for (int i = 0; i <= 638; ++i) {
    if (isA) {
      int sA = -1;
      if (i <= 511) sA = i;
      else if (i >= 513 && ((i-513)&1) == 0 && (i-513)/2 <= 62)
        sA = 512 + (i-513)/2;
      if (sA >= 0) {
        const f16* hrd = &g_h0[sA & 1][0][0];
        f16*       hwr = &g_h0[(sA+1) & 1][0][0];
        const int b0 = Mbase + mf*16 + quad*4;
        // prefetch epilogue operands (drain overlaps the big batch below)
        float hold[4], xv[4];
        #pragma unroll
        for (int reg = 0; reg < 4; ++reg) {
          hold[reg] = ld_f16_dc(&hrd[(size_t)(b0+reg)*HD + jcol]);
          xv[reg] = (sA < 512) ? (ctx[(b0+reg)*CTXL + sA] / scl[reg])
                               : ld_f32_dc(&g_yacc[sA-512][b0+reg]);
        }
        // batch ALL A-operand loads (32 b64 in flight, ONE drain point)
        const int arow = Mbase + mf*16 + l16;
        const f16* aptr = hrd + (size_t)arow*HD + quad*8;
        half8 av[16];
        #pragma unroll
        for (int kc = 0; kc < 16; ++kc) av[kc] = ld_half8_dc(aptr + kc*32);
        floatx4 ar = {0.f,0.f,0.f,0.f}, az = ar, an_ = ar;
        const f16* fb = wlds + (size_t)lane*8;       // fragment-linear base
        #pragma unroll
        for (int kc = 0; kc < 16; ++kc) {
          const f16* fkc = fb + (size_t)kc*512;
          half8 v;
          v = *(const half8*)(fkc);          ar  = __builtin_amdgcn_mfma_f32_16x16x32_f16(av[kc], v, ar,  0,0,0);
          v = *(const half8*)(fkc + 8192);   az  = __builtin_amdgcn_mfma_f32_16x16x32_f16(av[kc], v, az,  0,0,0);
          v = *(const half8*)(fkc + 16384);  an_ = __builtin_amdgcn_mfma_f32_16x16x32_f16(av[kc], v, an_, 0,0,0);
        }
        #pragma unroll
        for (int reg = 0; reg < 4; ++reg) {
          float hgr = ar[reg] + bh_r, hgz = az[reg] + bh_z, hgn = an_[reg] + bh_n;
          float rg  = sigm(fmaf(xv[reg], wi_r, bi_r) + hgr);
          float zg  = sigm(fmaf(xv[reg], wi_z, bi_z) + hgz);
          float ng_ = tanh_(fmaf(xv[reg], wi_n, bi_n) + rg*hgn);
          st_f16_dc(&hwr[(size_t)(b0+reg)*HD + jcol], (1.f - zg)*ng_ + zg*hold[reg]);
        }
        // same-address load-backs: returned => committed at MALL (coherence)
        #pragma unroll
        for (int reg = 0; reg < 4; ++reg)
          chk += ld_f16_dc(&hwr[(size_t)(b0+reg)*HD + jcol]);
      }
    } else {
      int sB = -1;
      if (i >= 1 && i <= 512) sB = i - 1;
      else if (i >= 514 && ((i-514)&1) == 0 && (i-514)/2 <= 62)
        sB = 512 + (i-514)/2;
      if (sB >= 0) {
        const f16* h0rd = &g_h0[(sB+1) & 1][0][0];   // layer-0 output of step sB
        const f16* h1rd = &g_h1[sB & 1][0][0];
        f16*       h1wr = &g_h1[(sB+1) & 1][0][0];
        const int b0 = Mbase + mf*16 + quad*4;
        float hold[4];
        #pragma unroll
        for (int reg = 0; reg < 4; ++reg)
          hold[reg] = ld_f16_dc(&h1rd[(size_t)(b0+reg)*HD + jcol]);
        // batch BOTH A-operand matrices (a1's drain overlaps a0's MFMA chain)
        const int arow = Mbase + mf*16 + l16;
        const f16* a0p = h0rd + (size_t)arow*HD + quad*8;
        const f16* a1p = h1rd + (size_t)arow*HD + quad*8;
        half8 a0v[16], a1v[16];
        #pragma unroll
        for (int kc = 0; kc < 16; ++kc) a0v[kc] = ld_half8_dc(a0p + kc*32);
        #pragma unroll
        for (int kc = 0; kc < 16; ++kc) a1v[kc] = ld_half8_dc(a1p + kc*32);
        floatx4 xr = {0.f,0.f,0.f,0.f}, xz = xr, xn = xr, hr = xr, hz = xr, hn = xr;
        const f16* fb = wlds + (size_t)lane*8;       // fragment-linear base
        #pragma unroll
        for (int kc = 0; kc < 16; ++kc) {
          const f16* fkc = fb + (size_t)kc*512;
          half8 v;
          v = *(const half8*)(fkc);           xr = __builtin_amdgcn_mfma_f32_16x16x32_f16(a0v[kc], v, xr, 0,0,0);
          v = *(const half8*)(fkc + 8192);    xz = __builtin_amdgcn_mfma_f32_16x16x32_f16(a0v[kc], v, xz, 0,0,0);
          v = *(const half8*)(fkc + 16384);   xn = __builtin_amdgcn_mfma_f32_16x16x32_f16(a0v[kc], v, xn, 0,0,0);
        }
        #pragma unroll
        for (int kc = 0; kc < 16; ++kc) {
          const f16* fkc = fb + (size_t)kc*512;
          half8 v;
          v = *(const half8*)(fkc + 24576);   hr = __builtin_amdgcn_mfma_f32_16x16x32_f16(a1v[kc], v, hr, 0,0,0);
          v = *(const half8*)(fkc + 32768);   hz = __builtin_amdgcn_mfma_f32_16x16x32_f16(a1v[kc], v, hz, 0,0,0);
          v = *(const half8*)(fkc + 40960);   hn = __builtin_amdgcn_mfma_f32_16x16x32_f16(a1v[kc], v, hn, 0,0,0);
        }
        #pragma unroll
        for (int reg = 0; reg < 4; ++reg) {
          const int b = b0 + reg;
          float rg  = sigm(xr[reg] + bi_r + hr[reg] + bh_r);
          float zg  = sigm(xz[reg] + bi_z + hz[reg] + bh_z);
          float ng_ = tanh_(xn[reg] + bi_n + rg*(hn[reg] + bh_n));
          float hnew = (1.f - zg)*ng_ + zg*hold[reg];
          st_f16_dc(&h1wr[(size_t)b*HD + jcol], hnew);
          if (sB >= 511) {                       // emit forecast partials
            float c = hnew * woutj;
            c += __shfl_xor(c, 1, 64); c += __shfl_xor(c, 2, 64);
            c += __shfl_xor(c, 4, 64); c += __shfl_xor(c, 8, 64);
            if (l16 == 0) {
              if (ng == 0) c += boutv;           // bias exactly once per row
              // RETURNING fetch_add: response implies commit at the MALL
              float old = __hip_atomic_fetch_add(&g_yacc[sB-511][b], c,
                            __ATOMIC_RELAXED, __HIP_MEMORY_SCOPE_AGENT);
              chk += old;
            }
          }
        }
        // same-address load-backs for the h1 stores
        #pragma unroll
        for (int reg = 0; reg < 4; ++reg)
          chk += ld_f16_dc(&h1wr[(size_t)(b0+reg)*HD + jcol]);
      }
    }
    sbar_fast(lines, rr_, (base + gen)*4u); gen++;
  }

  // never true (chk = sum of bounded h/y values); pins the load-backs
  if (chk == -1.25e38f) st_f32_dc(&g_scale[0], 0.f);

  // ---------------- stripe epoch advance + stripe-local output --------------
  if (rr_ == 0 && tid == 0)
    st_u32_dc(&g_sepoch[sid*64], E + 1u);

  if (tid < 64) {
    const int b = Mbase + tid;
    out[b*NPRED + rr_] = ld_f32_dc(&g_yacc[rr_][b]) * ld_f32_dc(&g_scale[b]);
  }
}

extern "C" void kernel_launch(void* const* d_in, const int* in_sizes, int n_in,
                              void* d_out, int out_size, void* d_ws, size_t ws_size,
                              hipStream_t stream) {
  const float* ctx   = (const float*)d_in[0];
  const float* Wih0  = (const float*)d_in[1];
  const float* Whh0  = (const float*)d_in[2];
  const float* bih0  = (const float*)d_in[3];
  const float* bhh0  = (const float*)d_in[4];
  const float* Wih1  = (const float*)d_in[5];
  const float* Whh1  = (const float*)d_in[6];
  const float* bih1  = (const float*)d_in[7];
  const float* bhh1  = (const float*)d_in[8];
  const float* Wout  = (const float*)d_in[9];
  const float* boutp = (const float*)d_in[10];
  float* out = (float*)d_out;

  hipFuncSetAttribute(reinterpret_cast<const void*>(rnn_persist),
                      hipFuncAttributeMaxDynamicSharedMemorySize, LDS_BYTES);

  void* params[] = {
    (void*)&ctx, (void*)&Wih0, (void*)&Whh0, (void*)&bih0, (void*)&bhh0,
    (void*)&Wih1, (void*)&Whh1, (void*)&bih1, (void*)&bhh1,
    (void*)&Wout, (void*)&boutp, (void*)&out
  };
  hipLaunchCooperativeKernel(reinterpret_cast<void*>(rnn_persist),
                             dim3(NBLK), dim3(NTHR), params, LDS_BYTES, stream);
}

// Round 16
// 6107.947 us; speedup vs baseline: 1.9598x; 1.1797x over previous
//
#include <hip/hip_runtime.h>

typedef unsigned int uint32;
typedef unsigned long long uint64;
typedef _Float16 f16;
typedef _Float16 half8 __attribute__((ext_vector_type(8)));
typedef float floatx4 __attribute__((ext_vector_type(4)));

#define HD    512    // hidden
#define NBAT  256    // batch
#define CTXL  512    // context length
#define NPRED 64     // prediction length
#define NBLK  256
#define NTHR  256
#define NSTR  4      // independent batch stripes (64 rows each)
#define LDS_BYTES (6*16*64*16)   // 98304 B: fragment-linear weights (B uses all, A half)
#define NGEN  575u               // role-intervals per launch (A: steps 0..574, B: 0..574)

// Scratch in device globals. ALL cross-block data via relaxed agent-scope
// atomics (MALL-direct). Producer protocol (R15-proven): store -> same-address
// load-back -> vmcnt drain (fence+syncthreads) -> relaxed arrival RMW.
// DECOUPLED SYNC (R16): separate A/B arrival-counter arrays per stripe.
//   A at sA: wait P_A>=sA (own), P_B>=sA-3 (h0 ring anti-clobber; >=sA in decode).
//   B at sB: wait P_A>=sB+1 (h0(sB) published; h0 batch load overlaps own poll),
//            then P_B>=sB (own).
// h0 is a 4-deep ring: h0(t) lives in slot t%4; A<=B+3 => live slots disjoint.
__device__ __attribute__((aligned(256))) f16   g_h0[4][NBAT][HD];
__device__ __attribute__((aligned(256))) f16   g_h1[2][NBAT][HD];
__device__ __attribute__((aligned(256))) float g_yacc[NPRED][NBAT];
__device__ __attribute__((aligned(256))) float g_scale[NBAT];
// Per stripe: 16 lines (64B apart) per role; 2 blocks arrive per line per gen.
__device__ __attribute__((aligned(256))) uint32 g_alines[NSTR*16*16];
__device__ __attribute__((aligned(256))) uint32 g_blines[NSTR*16*16];
__device__ __attribute__((aligned(256))) uint32 g_ilines[NSTR*16*16];  // init, 4/line
__device__ __attribute__((aligned(256))) uint32 g_sepoch[NSTR*64];     // launch count

__device__ __forceinline__ float sigm(float x){ return 1.f/(1.f+__expf(-x)); }
__device__ __forceinline__ float tanh_(float x){ return 1.f - 2.f/(__expf(2.f*x)+1.f); }

// ---- device-coherent (no-flush) access helpers -----------------------------
__device__ __forceinline__ uint32 ld_u32_dc(const uint32* p){
  return __hip_atomic_load(p, __ATOMIC_RELAXED, __HIP_MEMORY_SCOPE_AGENT);
}
__device__ __forceinline__ void st_u32_dc(uint32* p, uint32 v){
  __hip_atomic_store(p, v, __ATOMIC_RELAXED, __HIP_MEMORY_SCOPE_AGENT);
}
__device__ __forceinline__ void st_u64_dc(uint64* p, uint64 v){
  __hip_atomic_store(p, v, __ATOMIC_RELAXED, __HIP_MEMORY_SCOPE_AGENT);
}
__device__ __forceinline__ float ld_f32_dc(const float* p){
  return __hip_atomic_load(p, __ATOMIC_RELAXED, __HIP_MEMORY_SCOPE_AGENT);
}
__device__ __forceinline__ void st_f32_dc(float* p, float v){
  __hip_atomic_store(p, v, __ATOMIC_RELAXED, __HIP_MEMORY_SCOPE_AGENT);
}
__device__ __forceinline__ float ld_f16_dc(const f16* p){
  unsigned short u = __hip_atomic_load((const unsigned short*)p, __ATOMIC_RELAXED, __HIP_MEMORY_SCOPE_AGENT);
  union { unsigned short u; f16 h; } c; c.u = u; return (float)c.h;
}
__device__ __forceinline__ void st_f16_dc(f16* p, float x){
  union { unsigned short u; f16 h; } c; c.h = (f16)x;
  __hip_atomic_store((unsigned short*)p, c.u, __ATOMIC_RELAXED, __HIP_MEMORY_SCOPE_AGENT);
}
__device__ __forceinline__ half8 ld_half8_dc(const f16* p){   // 2x b64 coherent loads
  const uint64* q = (const uint64*)p;
  union { uint64 u[2]; half8 h; } r;
  r.u[0] = __hip_atomic_load(q+0, __ATOMIC_RELAXED, __HIP_MEMORY_SCOPE_AGENT);
  r.u[1] = __hip_atomic_load(q+1, __ATOMIC_RELAXED, __HIP_MEMORY_SCOPE_AGENT);
  return r.h;
}

// Wait until all 16 lines of `lines` reach tgt (wave-0 ballot gather), then
// syncthreads (releases waves 1-3 and acts as the compiler/memory fence that
// keeps subsequent data loads after the poll).
__device__ __forceinline__ void waitl(const uint32* lines, uint32 tgt){
  if (threadIdx.x < 64) {
    const int lane = threadIdx.x;
    const uint32* fp = &lines[(lane & 15)*16];
    for (;;) {
      bool ok = (lane >= 16) || ((int)(ld_u32_dc(fp) - tgt) >= 0);
      if (__ballot(ok) == ~0ull) break;
      __builtin_amdgcn_s_sleep(1);
    }
  }
  __syncthreads();
}
// Arrival: drain this block's stores+load-backs (fence+syncthreads), then one
// relaxed RMW (load-backs already proved data commit at the MALL — R15).
__device__ __forceinline__ void arrive(uint32* lines, int li){
  __builtin_amdgcn_fence(__ATOMIC_RELEASE, "workgroup");
  __syncthreads();
  if (threadIdx.x == 0)
    __hip_atomic_fetch_add(&lines[li*16], 1u, __ATOMIC_RELAXED, __HIP_MEMORY_SCOPE_AGENT);
}
__device__ __forceinline__ void arrive_rel(uint32* lines, int li){  // init only
  __builtin_amdgcn_fence(__ATOMIC_RELEASE, "workgroup");
  __syncthreads();
  if (threadIdx.x == 0)
    __hip_atomic_fetch_add(&lines[li*16], 1u, __ATOMIC_RELEASE, __HIP_MEMORY_SCOPE_AGENT);
}

// Persistent 2-layer GRU + AR decode; 4 independent 64-row stripes.
// Stripe s: blocks 64s..64s+63. rr<32: A (layer 0); rr>=32: B (layer 1).
// Weights in fragment-linear LDS (conflict-free, R12). Operands batch-loaded
// (one coherent drain per matrix, R13). Load-back producer ordering (R15).
__global__ __launch_bounds__(NTHR, 1) void rnn_persist(
    const float* __restrict__ ctx,    // [256][512] f32
    const float* __restrict__ Wih0,   // [1536]
    const float* __restrict__ Whh0,   // [1536][512]
    const float* __restrict__ bih0,   // [1536]
    const float* __restrict__ bhh0,   // [1536]
    const float* __restrict__ Wih1,   // [1536][512]
    const float* __restrict__ Whh1,   // [1536][512]
    const float* __restrict__ bih1,   // [1536]
    const float* __restrict__ bhh1,   // [1536]
    const float* __restrict__ Wout,   // [512]
    const float* __restrict__ boutp,  // [1]
    float* __restrict__ out)          // [256][64] f32
{
  extern __shared__ char smem_raw[];
  f16* wlds = (f16*)smem_raw;
  __shared__ float wsum[4];

  const int tid  = threadIdx.x;
  const int bid  = blockIdx.x;
  const int sid  = bid >> 6;         // stripe
  const int rr_  = bid & 63;
  const bool isA = rr_ < 32;
  const int ng   = isA ? rr_ : rr_ - 32;
  const int Mbase = sid * 64;        // batch-row base of stripe
  const int s0    = ng * 16;         // hidden-col base of this block
  const int w    = tid >> 6;
  const int lane = tid & 63;
  const int quad = lane >> 4;
  const int l16  = lane & 15;

  uint32* al = &g_alines[sid*256];
  uint32* bl = &g_blines[sid*256];
  uint32* il = &g_ilines[sid*256];
  const uint32 E = ld_u32_dc(&g_sepoch[sid*64]);
  const uint32 baseA = E * (2u*NGEN);
  const uint32 baseB = E * (2u*NGEN);

  // ---------------- init (stripe-local): scale, zero h0 slot3/h1/y ----------
  {
    const int b = bid;               // block bid handles batch row bid
    float s2 = 0.f;
    for (int k = tid; k < CTXL; k += NTHR) s2 += ctx[b*CTXL + k];
    #pragma unroll
    for (int m = 1; m < 64; m <<= 1) s2 += __shfl_xor(s2, m, 64);
    if (lane == 0) wsum[w] = s2;
    __syncthreads();
    float tot = wsum[0] + wsum[1] + wsum[2] + wsum[3];
    float sc  = fmaxf(fabsf(tot / (float)CTXL), 1e-5f);
    if (tid == 0) st_f32_dc(&g_scale[b], sc);
    uint64* h03 = (uint64*)&g_h0[3][b][0];   // h0(-1)
    uint64* h10 = (uint64*)&g_h1[0][b][0];   // h1(-1)
    uint64* h11 = (uint64*)&g_h1[1][b][0];
    for (int k = tid; k < HD/4; k += NTHR) {
      st_u64_dc(h03+k, 0ull); st_u64_dc(h10+k, 0ull); st_u64_dc(h11+k, 0ull);
    }
    if (tid < 64) st_f32_dc(&g_yacc[rr_][Mbase + tid], 0.f);
  }

  // -------- weights -> fragment-linear LDS (f32 -> f16, conflict-free) ------
  {
    const int nfrag = isA ? (3*16*64) : (6*16*64);
    for (int idx = tid; idx < nfrag; idx += NTHR) {
      const int ln = idx & 63;
      const int kc = (idx >> 6) & 15;
      const int mg = idx >> 10;
      const float* Wsrc;
      int g;
      if (isA)            { Wsrc = Whh0; g = mg; }
      else if (mg < 3)    { Wsrc = Wih1; g = mg; }
      else                { Wsrc = Whh1; g = mg - 3; }
      const float* src = Wsrc + (size_t)(g*HD + s0 + (ln & 15))*HD + (ln >> 4)*8 + kc*32;
      f16* dst = wlds + (size_t)idx*8;
      #pragma unroll
      for (int j = 0; j < 8; ++j) dst[j] = (f16)src[j];
    }
  }

  // ---------------- per-thread constants ------------------------------------
  float wi_r=0, wi_z=0, wi_n=0, bi_r, bi_z, bi_n, bh_r, bh_z, bh_n;
  float woutj=0, boutv=0;
  const int jcol = s0 + l16;
  const int mf = w;                  // 4 waves x 16 batch rows = 64 rows
  if (isA) {
    wi_r = Wih0[jcol]; wi_z = Wih0[HD + jcol]; wi_n = Wih0[2*HD + jcol];
    bi_r = bih0[jcol]; bi_z = bih0[HD + jcol]; bi_n = bih0[2*HD + jcol];
    bh_r = bhh0[jcol]; bh_z = bhh0[HD + jcol]; bh_n = bhh0[2*HD + jcol];
  } else {
    bi_r = bih1[jcol]; bi_z = bih1[HD + jcol]; bi_n = bih1[2*HD + jcol];
    bh_r = bhh1[jcol]; bh_z = bhh1[HD + jcol]; bh_n = bhh1[2*HD + jcol];
    woutj = Wout[jcol]; boutv = boutp[0];
  }

  // strong init barrier (release arrival + agent acquire, once per launch)
  arrive_rel(il, rr_ & 15);
  waitl(il, E*4u + 4u);
  __builtin_amdgcn_fence(__ATOMIC_ACQUIRE, "agent");
  __syncthreads();

  // preload scale for my 4 output rows
  float scl[4];
  {
    const int bb = Mbase + mf*16 + quad*4;
    #pragma unroll
    for (int reg = 0; reg < 4; ++reg) scl[reg] = ld_f32_dc(&g_scale[bb + reg]);
  }

  float chk = 0.f;   // load-back accumulator; guard below is never true

  // ---------------- role loops ----------------------------------------------
  if (isA) {
    for (int sA = 0; sA < (int)NGEN; ++sA) {
      waitl(al, baseA + 2u*(uint32)sA);              // own: all A done sA-1
      const f16* hrd = &g_h0[(sA+3)&3][0][0];        // h0(sA-1)
      f16*       hwr = &g_h0[sA&3][0][0];            // h0(sA)
      const int b0 = Mbase + mf*16 + quad*4;
      float hold[4], xv[4];
      #pragma unroll
      for (int reg = 0; reg < 4; ++reg)
        hold[reg] = ld_f16_dc(&hrd[(size_t)(b0+reg)*HD + jcol]);
      const int arow = Mbase + mf*16 + l16;
      const f16* aptr = hrd + (size_t)arow*HD + quad*8;
      half8 av[16];
      #pragma unroll
      for (int kc = 0; kc < 16; ++kc) av[kc] = ld_half8_dc(aptr + kc*32);
      if (sA < 512) {
        #pragma unroll
        for (int reg = 0; reg < 4; ++reg)
          xv[reg] = ctx[(b0+reg)*CTXL + sA] / scl[reg];
        if (sA >= 4) waitl(bl, baseB + 2u*(uint32)(sA-3));  // ring anti-clobber
      } else {
        waitl(bl, baseB + 2u*(uint32)sA);            // y(sA-512) ready (subsumes)
        #pragma unroll
        for (int reg = 0; reg < 4; ++reg)
          xv[reg] = ld_f32_dc(&g_yacc[sA-512][b0+reg]);
      }
      floatx4 ar = {0.f,0.f,0.f,0.f}, az = ar, an_ = ar;
      const f16* fb = wlds + (size_t)lane*8;
      #pragma unroll
      for (int kc = 0; kc < 16; ++kc) {
        const f16* fkc = fb + (size_t)kc*512;
        half8 v;
        v = *(const half8*)(fkc);          ar  = __builtin_amdgcn_mfma_f32_16x16x32_f16(av[kc], v, ar,  0,0,0);
        v = *(const half8*)(fkc + 8192);   az  = __builtin_amdgcn_mfma_f32_16x16x32_f16(av[kc], v, az,  0,0,0);
        v = *(const half8*)(fkc + 16384);  an_ = __builtin_amdgcn_mfma_f32_16x16x32_f16(av[kc], v, an_, 0,0,0);
      }
      #pragma unroll
      for (int reg = 0; reg < 4; ++reg) {
        float hgr = ar[reg] + bh_r, hgz = az[reg] + bh_z, hgn = an_[reg] + bh_n;
        float rg  = sigm(fmaf(xv[reg], wi_r, bi_r) + hgr);
        float zg  = sigm(fmaf(xv[reg], wi_z, bi_z) + hgz);
        float ng_ = tanh_(fmaf(xv[reg], wi_n, bi_n) + rg*hgn);
        st_f16_dc(&hwr[(size_t)(b0+reg)*HD + jcol], (1.f - zg)*ng_ + zg*hold[reg]);
      }
      #pragma unroll
      for (int reg = 0; reg < 4; ++reg)        // load-backs prove commit
        chk += ld_f16_dc(&hwr[(size_t)(b0+reg)*HD + jcol]);
      arrive(al, rr_ & 15);
    }
  } else {
    for (int sB = 0; sB < (int)NGEN; ++sB) {
      waitl(al, baseA + 2u*(uint32)(sB+1));          // h0(sB) published
      const f16* h0rd = &g_h0[sB&3][0][0];
      const int arow = Mbase + mf*16 + l16;
      const f16* a0p = h0rd + (size_t)arow*HD + quad*8;
      half8 a0v[16];
      #pragma unroll
      for (int kc = 0; kc < 16; ++kc) a0v[kc] = ld_half8_dc(a0p + kc*32);
      waitl(bl, baseB + 2u*(uint32)sB);              // own: all B done sB-1
      const f16* h1rd = &g_h1[sB&1][0][0];
      f16*       h1wr = &g_h1[(sB+1)&1][0][0];
      const int b0 = Mbase + mf*16 + quad*4;
      float hold[4];
      #pragma unroll
      for (int reg = 0; reg < 4; ++reg)
        hold[reg] = ld_f16_dc(&h1rd[(size_t)(b0+reg)*HD + jcol]);
      const f16* a1p = h1rd + (size_t)arow*HD + quad*8;
      half8 a1v[16];
      #pragma unroll
      for (int kc = 0; kc < 16; ++kc) a1v[kc] = ld_half8_dc(a1p + kc*32);
      floatx4 xr = {0.f,0.f,0.f,0.f}, xz = xr, xn = xr, hr = xr, hz = xr, hn = xr;
      const f16* fb = wlds + (size_t)lane*8;
      #pragma unroll
      for (int kc = 0; kc < 16; ++kc) {
        const f16* fkc = fb + (size_t)kc*512;
        half8 v;
        v = *(const half8*)(fkc);           xr = __builtin_amdgcn_mfma_f32_16x16x32_f16(a0v[kc], v, xr, 0,0,0);
        v = *(const half8*)(fkc + 8192);    xz = __builtin_amdgcn_mfma_f32_16x16x32_f16(a0v[kc], v, xz, 0,0,0);
        v = *(const half8*)(fkc + 16384);   xn = __builtin_amdgcn_mfma_f32_16x16x32_f16(a0v[kc], v, xn, 0,0,0);
      }
      #pragma unroll
      for (int kc = 0; kc < 16; ++kc) {
        const f16* fkc = fb + (size_t)kc*512;
        half8 v;
        v = *(const half8*)(fkc + 24576);   hr = __builtin_amdgcn_mfma_f32_16x16x32_f16(a1v[kc], v, hr, 0,0,0);
        v = *(const half8*)(fkc + 32768);   hz = __builtin_amdgcn_mfma_f32_16x16x32_f16(a1v[kc], v, hz, 0,0,0);
        v = *(const half8*)(fkc + 40960);   hn = __builtin_amdgcn_mfma_f32_16x16x32_f16(a1v[kc], v, hn, 0,0,0);
      }
      #pragma unroll
      for (int reg = 0; reg < 4; ++reg) {
        const int b = b0 + reg;
        float rg  = sigm(xr[reg] + bi_r + hr[reg] + bh_r);
        float zg  = sigm(xz[reg] + bi_z + hz[reg] + bh_z);
        float ng_ = tanh_(xn[reg] + bi_n + rg*(hn[reg] + bh_n));
        float hnew = (1.f - zg)*ng_ + zg*hold[reg];
        st_f16_dc(&h1wr[(size_t)b*HD + jcol], hnew);
        if (sB >= 511) {                     // forecast partials, p = sB-511
          float c = hnew * woutj;
          c += __shfl_xor(c, 1, 64); c += __shfl_xor(c, 2, 64);
          c += __shfl_xor(c, 4, 64); c += __shfl_xor(c, 8, 64);
          if (l16 == 0) {
            if (ng == 0) c += boutv;
            float old = __hip_atomic_fetch_add(&g_yacc[sB-511][b], c,
                          __ATOMIC_RELAXED, __HIP_MEMORY_SCOPE_AGENT);
            chk += old;                      // returning add == its own load-back
          }
        }
      }
      #pragma unroll
      for (int reg = 0; reg < 4; ++reg)      // load-backs prove commit
        chk += ld_f16_dc(&h1wr[(size_t)(b0+reg)*HD + jcol]);
      arrive(bl, ng & 15);
    }
  }

  // never true (chk = sum of bounded h/y values); pins the load-backs
  if (chk == -1.25e38f) st_f32_dc(&g_scale[0], 0.f);

  // ---------------- final: wait all B done, output, epoch advance -----------
  waitl(bl, baseB + 2u*NGEN);
  if (tid < 64) {
    const int b = Mbase + tid;
    out[b*NPRED + rr_] = ld_f32_dc(&g_yacc[rr_][b]) * ld_f32_dc(&g_scale[b]);
  }
  if (rr_ == 0) {
    waitl(al, baseA + 2u*NGEN);
    if (tid == 0) st_u32_dc(&g_sepoch[sid*64], E + 1u);
  }
}

extern "C" void kernel_launch(void* const* d_in, const int* in_sizes, int n_in,
                              void* d_out, int out_size, void* d_ws, size_t ws_size,
                              hipStream_t stream) {
  const float* ctx   = (const float*)d_in[0];
  const float* Wih0  = (const float*)d_in[1];
  const float* Whh0  = (const float*)d_in[2];
  const float* bih0  = (const float*)d_in[3];
  const float* bhh0  = (const float*)d_in[4];
  const float* Wih1  = (const float*)d_in[5];
  const float* Whh1  = (const float*)d_in[6];
  const float* bih1  = (const float*)d_in[7];
  const float* bhh1  = (const float*)d_in[8];
  const float* Wout  = (const float*)d_in[9];
  const float* boutp = (const float*)d_in[10];
  float* out = (float*)d_out;

  hipFuncSetAttribute(reinterpret_cast<const void*>(rnn_persist),
                      hipFuncAttributeMaxDynamicSharedMemorySize, LDS_BYTES);

  void* params[] = {
    (void*)&ctx, (void*)&Wih0, (void*)&Whh0, (void*)&bih0, (void*)&bhh0,
    (void*)&Wih1, (void*)&Whh1, (void*)&bih1, (void*)&bhh1,
    (void*)&Wout, (void*)&boutp, (void*)&out
  };
  hipLaunchCooperativeKernel(reinterpret_cast<void*>(rnn_persist),
                             dim3(NBLK), dim3(NTHR), params, LDS_BYTES, stream);
}